// Round 3
// baseline (52540.576 us; speedup 1.0000x reference)
//
#include <hip/hip_runtime.h>

typedef __attribute__((ext_vector_type(8))) short bf8;
typedef __attribute__((ext_vector_type(8))) unsigned short us8;
typedef __attribute__((ext_vector_type(4))) unsigned short us4;
typedef __attribute__((ext_vector_type(4))) float f4;

#define NB 256
#define NBLK 256
#define OUT_HX_OFF ((size_t)256 * 256 * 1024)
#define OUT_CX_OFF (OUT_HX_OFF + (size_t)256 * 1024)

static __device__ __forceinline__ unsigned short f2bf(float f) {
    unsigned u = __builtin_bit_cast(unsigned, f);
    return (unsigned short)((u + 0x7FFFu + ((u >> 16) & 1u)) >> 16);
}
static __device__ __forceinline__ float bf2f(unsigned short h) {
    return __builtin_bit_cast(float, (unsigned)h << 16);
}
static __device__ __forceinline__ float sigm(float x) {
    return 1.0f / (1.0f + __expf(-x));
}

#define MFMA16(a, b, c) __builtin_amdgcn_mfma_f32_16x16x32_bf16(a, b, c, 0, 0, 0)

#define GLDS16(g, l)                                                        \
    __builtin_amdgcn_global_load_lds(                                       \
        (const __attribute__((address_space(1))) void*)(g),                 \
        (__attribute__((address_space(3))) void*)(l), 16, 0, 0)

#define WAITV(n) asm volatile("s_waitcnt vmcnt(" #n ")" ::: "memory")
#define WAITL0 asm volatile("s_waitcnt lgkmcnt(0)" ::: "memory")
#define BARRIER                                                             \
    do {                                                                    \
        __builtin_amdgcn_s_barrier();                                       \
        __builtin_amdgcn_sched_barrier(0);                                  \
    } while (0)

// Stage R rows x 64 bf16 cols into LDS (linear row-major, 128B rows) via
// global_load_lds.  Source chunk is pre-swizzled (chunk ^= row&7) so the
// read side XORs the same way -> conflict-free-ish ds_read_b128.
template <int R>
static __device__ __forceinline__ void stage64(const unsigned short* g, int gstride,
                                               unsigned short* lds, int wave, int lane) {
#pragma unroll
    for (int j = 0; j < R / 32; ++j) {
        const int seg = wave * (R / 32) + j;
        const int row = seg * 8 + (lane >> 3);
        const int chunk = (lane & 7) ^ (row & 7);
        GLDS16(g + (size_t)row * gstride + chunk * 8, lds + seg * 512);
    }
}

static __device__ __forceinline__ bf8 fragld(const unsigned short* lds, int row, int ck) {
    return *(const bf8*)&lds[row * 64 + (((ck) ^ (row & 7)) << 3)];
}

// Epoch-based device-scope grid barrier (all NBLK blocks resident: grid=256=#CUs,
// LDS 72KB -> >=2 blocks/CU capacity, so the full grid is always co-resident).
static __device__ __forceinline__ void gbar(int* bar) {
    __syncthreads();   // compiler emits full vmcnt/lgkm drain before s_barrier
    if (threadIdx.x == 0) {
        int g = __hip_atomic_load(bar + 1, __ATOMIC_RELAXED, __HIP_MEMORY_SCOPE_AGENT);
        int v = __hip_atomic_fetch_add(bar, 1, __ATOMIC_ACQ_REL, __HIP_MEMORY_SCOPE_AGENT);
        if (v == NBLK - 1) {
            __hip_atomic_store(bar, 0, __ATOMIC_RELAXED, __HIP_MEMORY_SCOPE_AGENT);
            __hip_atomic_store(bar + 1, g + 1, __ATOMIC_RELEASE, __HIP_MEMORY_SCOPE_AGENT);
        } else {
            while (__hip_atomic_load(bar + 1, __ATOMIC_ACQUIRE, __HIP_MEMORY_SCOPE_AGENT) == g)
                __builtin_amdgcn_s_sleep(1);
        }
    }
    __syncthreads();
}

// ---------------- one-time: f32 -> bf16 convert ----------------
__global__ __launch_bounds__(256) void k_x2bf(const float* __restrict__ src,
                                              unsigned short* __restrict__ dst, int n4) {
    const int stride = gridDim.x * 256;
    for (int i = blockIdx.x * 256 + threadIdx.x; i < n4; i += stride) {
        f4 v = ((const f4*)src)[i];
        us4 o;
        o[0] = f2bf(v[0]); o[1] = f2bf(v[1]); o[2] = f2bf(v[2]); o[3] = f2bf(v[3]);
        ((us4*)dst)[i] = o;
    }
}

// ---------------- one-time: weight transpose f32[K][N] -> bf16[N][K] ----------------
__global__ __launch_bounds__(256) void k_transpose(const float* __restrict__ src,
                                                   unsigned short* __restrict__ dst,
                                                   int K, int N) {
    __shared__ float tile[32][33];
    const int tx = threadIdx.x & 31, ty = threadIdx.x >> 5;
    const int n0 = blockIdx.x * 32, k0 = blockIdx.y * 32;
#pragma unroll
    for (int i = 0; i < 4; ++i) tile[ty + i * 8][tx] = src[(size_t)(k0 + ty + i * 8) * N + n0 + tx];
    __syncthreads();
#pragma unroll
    for (int i = 0; i < 4; ++i)
        dst[(size_t)(n0 + ty + i * 8) * K + k0 + tx] = f2bf(tile[tx][ty + i * 8]);
}

// ---------------- one-time: xpre = X @ Wg_x + bg  (M=65536, N=4096, K=1024) ----------------
__global__ __launch_bounds__(256) void k_xpre(const unsigned short* __restrict__ xbf,
                                              const unsigned short* __restrict__ wgT,
                                              const float* __restrict__ bg,
                                              unsigned short* __restrict__ xpre) {
    __shared__ unsigned short sA[2][128 * 64];
    __shared__ unsigned short sB[2][128 * 64];
    const int tid = threadIdx.x, lane = tid & 63, wave = tid >> 6;
    const int n0 = blockIdx.x * 128;
    const size_t m0 = (size_t)blockIdx.y * 128;
    const int wy = (wave >> 1) * 64, wx = (wave & 1) * 64;
    const int fr = lane & 15, fq = lane >> 4;
    f4 acc[4][4] = {};

    stage64<128>(xbf + m0 * 1024, 1024, sA[0], wave, lane);
    stage64<128>(wgT + (size_t)n0 * 2048, 2048, sB[0], wave, lane);
    WAITV(0); BARRIER;
#pragma unroll
    for (int i = 0; i < 16; ++i) {
        if (i + 1 < 16) {
            stage64<128>(xbf + m0 * 1024 + (i + 1) * 64, 1024, sA[(i + 1) & 1], wave, lane);
            stage64<128>(wgT + (size_t)n0 * 2048 + (i + 1) * 64, 2048, sB[(i + 1) & 1], wave, lane);
        }
        const unsigned short* A = sA[i & 1];
        const unsigned short* Bm = sB[i & 1];
#pragma unroll
        for (int ks = 0; ks < 2; ++ks) {
            bf8 af[4], bfv[4];
#pragma unroll
            for (int mi = 0; mi < 4; ++mi) af[mi] = fragld(A, wy + mi * 16 + fr, ks * 4 + fq);
#pragma unroll
            for (int ni = 0; ni < 4; ++ni) bfv[ni] = fragld(Bm, wx + ni * 16 + fr, ks * 4 + fq);
#pragma unroll
            for (int mi = 0; mi < 4; ++mi)
#pragma unroll
                for (int ni = 0; ni < 4; ++ni)
                    acc[mi][ni] = MFMA16(af[mi], bfv[ni], acc[mi][ni]);
        }
        if (i + 1 < 16) { WAITL0; WAITV(0); BARRIER; }
    }
#pragma unroll
    for (int mi = 0; mi < 4; ++mi)
#pragma unroll
        for (int ni = 0; ni < 4; ++ni) {
            const int col = n0 + wx + ni * 16 + fr;
            const float b = bg[col];
#pragma unroll
            for (int j = 0; j < 4; ++j) {
                const size_t row = m0 + wy + mi * 16 + fq * 4 + j;
                xpre[row * 4096 + col] = f2bf(acc[mi][ni][j] + b);
            }
        }
}

// ---------------- persistent kernel: all 256 timesteps, 4 phases/step ----------------
// TIER 1: xin = xpre [T][256][4096] (bg already folded in).
// TIER 2: xin = xbf  [T][256][1024].
// TIER 3: xin = small double-buffer [2][256][1024]; x(t+1) converted during S4.
template <int TIER>
__global__ __launch_bounds__(256, 1) void k_seq(
    unsigned short* xin, const float* xf32,
    const unsigned short* wgT, const float* bg,
    const unsigned short* wqkvT, const float* bq, const float* bk, const float* bv,
    const unsigned short* woT, const float* bo,
    unsigned short* hxbf, unsigned short* prebf, float* gupd,
    unsigned short* qkvbf, unsigned short* aobf,
    float* out, int* bar) {
    __shared__ unsigned short smem[36864];  // 72 KiB, re-carved per phase
    const int tid = threadIdx.x, lane = tid & 63, wave = tid >> 6;
    const int bid = blockIdx.x;
    const int fr = lane & 15, fq = lane >> 4;

    if (TIER == 3) {  // convert x_0 into buffer 0
        const int idx = bid * 256 + tid;
        f4 v = ((const f4*)xf32)[idx];
        us4 o;
        o[0] = f2bf(v[0]); o[1] = f2bf(v[1]); o[2] = f2bf(v[2]); o[3] = f2bf(v[3]);
        ((us4*)xin)[idx] = o;
        gbar(bar);
    }

    for (int t = 0; t < 256; ++t) {
        // ---------------- S1: pre-gate GEMM ----------------
        {
            const int n0 = (bid & 63) * 64, b0 = (bid >> 6) * 64;
            unsigned short* sA = smem;
            unsigned short* sB = smem + 12288;
            constexpr int NT = (TIER == 1) ? 16 : 32;
            const unsigned short* xt;
            if (TIER == 1) xt = xin + (size_t)t * 256 * 4096;
            else if (TIER == 2) xt = xin + (size_t)t * 256 * 1024;
            else xt = xin + (size_t)(t & 1) * 262144;
            const unsigned short* hb = hxbf + (size_t)b0 * 1024;
            const unsigned short* xb = xt + (TIER == 1 ? 0 : (size_t)b0 * 1024);

            auto asrc = [&](int i) -> const unsigned short* {
                if (TIER == 1) return hb + i * 64;
                return i < 16 ? xb + i * 64 : hb + (i - 16) * 64;
            };
            auto bsrc = [&](int i) -> const unsigned short* {
                return wgT + (size_t)n0 * 2048 + (TIER == 1 ? 1024 : 0) + i * 64;
            };
            const int wr = (wave >> 1) * 32, wc = (wave & 1) * 32;
            f4 acc[2][2] = {};

            stage64<64>(asrc(0), 1024, sA, wave, lane);
            stage64<64>(bsrc(0), 2048, sB, wave, lane);
            stage64<64>(asrc(1), 1024, sA + 4096, wave, lane);
            stage64<64>(bsrc(1), 2048, sB + 4096, wave, lane);
            WAITV(4); BARRIER;
#pragma unroll
            for (int i = 0; i < NT; ++i) {
                if (i + 2 < NT) {
                    stage64<64>(asrc(i + 2), 1024, sA + ((i + 2) % 3) * 4096, wave, lane);
                    stage64<64>(bsrc(i + 2), 2048, sB + ((i + 2) % 3) * 4096, wave, lane);
                }
                const unsigned short* A = sA + (i % 3) * 4096;
                const unsigned short* Bm = sB + (i % 3) * 4096;
#pragma unroll
                for (int ks = 0; ks < 2; ++ks) {
                    bf8 a0 = fragld(A, wr + fr, ks * 4 + fq);
                    bf8 a1 = fragld(A, wr + 16 + fr, ks * 4 + fq);
                    bf8 b0v = fragld(Bm, wc + fr, ks * 4 + fq);
                    bf8 b1v = fragld(Bm, wc + 16 + fr, ks * 4 + fq);
                    acc[0][0] = MFMA16(a0, b0v, acc[0][0]);
                    acc[0][1] = MFMA16(a0, b1v, acc[0][1]);
                    acc[1][0] = MFMA16(a1, b0v, acc[1][0]);
                    acc[1][1] = MFMA16(a1, b1v, acc[1][1]);
                }
                if (i < NT - 1) {
                    WAITL0;
                    if (i + 2 < NT) { WAITV(4); } else { WAITV(0); }
                    BARRIER;
                }
            }
#pragma unroll
            for (int mi = 0; mi < 2; ++mi)
#pragma unroll
                for (int ni = 0; ni < 2; ++ni) {
                    const int col = n0 + wc + ni * 16 + fr;
                    const int gg = col >> 10, d = col & 1023;
#pragma unroll
                    for (int j = 0; j < 4; ++j) {
                        const int row = b0 + wr + mi * 16 + fq * 4 + j;
                        float v = acc[mi][ni][j];
                        if (TIER == 1) v += bf2f(xt[(size_t)row * 4096 + col]);
                        else v += bg[col];
                        if (gg == 2) {
                            gupd[(size_t)row * 1024 + d] = tanhf(v);
                        } else {
                            const int gm = (gg == 3) ? 2 : gg;
                            prebf[((size_t)gm * NB + row) * 1024 + d] = f2bf(v);
                        }
                    }
                }
        }
        gbar(bar);

        // ---------------- S2: QKV GEMMs (288 tiles of 128x64 over 256 blocks) ----------------
        {
            unsigned short* sA = smem;           // 3 x 128*64
            unsigned short* sB = smem + 24576;   // 3 x 64*64
            const int wy = (wave >> 1) * 64, wx = (wave & 1) * 32;
            for (int tl = bid; tl < 288; tl += NBLK) {
                WAITL0;  // drain ds_reads of previous tile before re-staging LDS
                const int g = tl / 96, rem = tl % 96;
                const int b0 = (rem / 48) * 128, n0 = (rem % 48) * 64;
                const unsigned short* Aab = prebf + ((size_t)g * NB + b0) * 1024;
                const unsigned short* Bb = wqkvT + ((size_t)g * 3072 + n0) * 1024;
                f4 acc[4][2] = {};

                stage64<128>(Aab, 1024, sA, wave, lane);
                stage64<64>(Bb, 1024, sB, wave, lane);
                stage64<128>(Aab + 64, 1024, sA + 8192, wave, lane);
                stage64<64>(Bb + 64, 1024, sB + 4096, wave, lane);
                WAITV(6); BARRIER;
#pragma unroll
                for (int i = 0; i < 16; ++i) {
                    if (i + 2 < 16) {
                        stage64<128>(Aab + (i + 2) * 64, 1024, sA + ((i + 2) % 3) * 8192, wave, lane);
                        stage64<64>(Bb + (i + 2) * 64, 1024, sB + ((i + 2) % 3) * 4096, wave, lane);
                    }
                    const unsigned short* A = sA + (i % 3) * 8192;
                    const unsigned short* Bm = sB + (i % 3) * 4096;
#pragma unroll
                    for (int ks = 0; ks < 2; ++ks) {
                        bf8 af[4], bv2[2];
#pragma unroll
                        for (int mi = 0; mi < 4; ++mi)
                            af[mi] = fragld(A, wy + mi * 16 + fr, ks * 4 + fq);
#pragma unroll
                        for (int ni = 0; ni < 2; ++ni)
                            bv2[ni] = fragld(Bm, wx + ni * 16 + fr, ks * 4 + fq);
#pragma unroll
                        for (int mi = 0; mi < 4; ++mi)
#pragma unroll
                            for (int ni = 0; ni < 2; ++ni)
                                acc[mi][ni] = MFMA16(af[mi], bv2[ni], acc[mi][ni]);
                    }
                    if (i < 15) {
                        WAITL0;
                        if (i + 2 < 16) { WAITV(6); } else { WAITV(0); }
                        BARRIER;
                    }
                }
#pragma unroll
                for (int mi = 0; mi < 4; ++mi)
#pragma unroll
                    for (int ni = 0; ni < 2; ++ni) {
                        const int col = n0 + wx + ni * 16 + fr;
                        const int which = col >> 10, d = col & 1023;
                        const float* bp = which == 0 ? bq : (which == 1 ? bk : bv);
                        const float bias = bp[g * 1024 + d];
#pragma unroll
                        for (int j = 0; j < 4; ++j) {
                            const int row = b0 + wy + mi * 16 + fq * 4 + j;
                            qkvbf[((size_t)g * NB + row) * 3072 + col] = f2bf(acc[mi][ni][j] + bias);
                        }
                    }
            }
        }
        gbar(bar);

        // ---------------- S3: cross-head attention (1 batch per block) ----------------
        {
            const int b = bid;
            unsigned short* qs = smem;
            unsigned short* ks2 = smem + 3456;
            unsigned short* vs = smem + 6912;
            float* aw = (float*)(smem + 10368);  // [3][16][17]
#pragma unroll
            for (int j = 0; j < 9; ++j) {
                const int lin = j * 256 + tid;
                const int g = lin / 768, n = (lin % 768) * 4;
                us4 dv = *(const us4*)(qkvbf + ((size_t)g * NB + b) * 3072 + n);
                const int part = n >> 10, h = (n >> 6) & 15, c = n & 63;
                unsigned short* base = part == 0 ? qs : (part == 1 ? ks2 : vs);
                *(us4*)&base[(g * 16 + h) * 72 + c] = dv;
            }
            __syncthreads();
            const int h = tid >> 4, kp = tid & 15;
#pragma unroll
            for (int g = 0; g < 3; ++g) {
                float s = 0.f;
#pragma unroll
                for (int dblk = 0; dblk < 8; ++dblk) {
                    us8 qv = *(const us8*)&qs[(g * 16 + h) * 72 + dblk * 8];
                    us8 kv = *(const us8*)&ks2[(g * 16 + kp) * 72 + dblk * 8];
#pragma unroll
                    for (int e = 0; e < 8; ++e) s += bf2f(qv[e]) * bf2f(kv[e]);
                }
                s *= 0.125f;
                float m = s;
#pragma unroll
                for (int off = 8; off; off >>= 1) m = fmaxf(m, __shfl_xor(m, off, 16));
                const float p = __expf(s - m);
                float sum = p;
#pragma unroll
                for (int off = 8; off; off >>= 1) sum += __shfl_xor(sum, off, 16);
                aw[(g * 16 + h) * 17 + kp] = p / sum;
            }
            __syncthreads();
#pragma unroll
            for (int g = 0; g < 3; ++g) {
                float a0 = 0.f, a1 = 0.f, a2 = 0.f, a3 = 0.f;
#pragma unroll
                for (int kk = 0; kk < 16; ++kk) {
                    const float w = aw[(g * 16 + h) * 17 + kk];
                    us4 vv = *(const us4*)&vs[(g * 16 + kk) * 72 + kp * 4];
                    a0 += w * bf2f(vv[0]); a1 += w * bf2f(vv[1]);
                    a2 += w * bf2f(vv[2]); a3 += w * bf2f(vv[3]);
                }
                us4 ov;
                ov[0] = f2bf(a0); ov[1] = f2bf(a1); ov[2] = f2bf(a2); ov[3] = f2bf(a3);
                *(us4*)(aobf + ((size_t)g * NB + b) * 1024 + h * 64 + kp * 4) = ov;
            }
        }
        gbar(bar);

        // ---------------- S4: output-gate GEMMs + cell update ----------------
        {
            unsigned short* sA = smem;          // 3 x 32*64
            unsigned short* sB = smem + 6144;
            const int d0 = (bid & 31) * 32, b0 = (bid >> 5) * 32;
            const int wr = (wave >> 1) * 16, wc = (wave & 1) * 16;
            f4 acc[3] = {};

            auto asrc = [&](int i) -> const unsigned short* {
                return aobf + ((size_t)(i >> 4) * NB + b0) * 1024 + (i & 15) * 64;
            };
            auto bsrc = [&](int i) -> const unsigned short* {
                return woT + ((size_t)(i >> 4) * 1024 + d0) * 1024 + (i & 15) * 64;
            };
            WAITL0;
            stage64<32>(asrc(0), 1024, sA, wave, lane);
            stage64<32>(bsrc(0), 1024, sB, wave, lane);
            stage64<32>(asrc(1), 1024, sA + 2048, wave, lane);
            stage64<32>(bsrc(1), 1024, sB + 2048, wave, lane);
            WAITV(2); BARRIER;
#pragma unroll
            for (int i = 0; i < 48; ++i) {
                if (i + 2 < 48) {
                    stage64<32>(asrc(i + 2), 1024, sA + ((i + 2) % 3) * 2048, wave, lane);
                    stage64<32>(bsrc(i + 2), 1024, sB + ((i + 2) % 3) * 2048, wave, lane);
                }
                const unsigned short* A = sA + (i % 3) * 2048;
                const unsigned short* Bm = sB + (i % 3) * 2048;
#pragma unroll
                for (int ks = 0; ks < 2; ++ks) {
                    bf8 a0 = fragld(A, wr + fr, ks * 4 + fq);
                    bf8 b0v = fragld(Bm, wc + fr, ks * 4 + fq);
                    acc[i >> 4] = MFMA16(a0, b0v, acc[i >> 4]);
                }
                if (i < 47) {
                    WAITL0;
                    if (i + 2 < 48) { WAITV(2); } else { WAITV(0); }
                    BARRIER;
                }
            }

            const int col = d0 + wc + fr;
            const float bof = bo[col], boi = bo[1024 + col], boo = bo[2048 + col];
            float* cxp = out + OUT_CX_OFF;
            float* hxp = out + OUT_HX_OFF;
            float* outs = out + (size_t)t * NB * 1024;
#pragma unroll
            for (int j = 0; j < 4; ++j) {
                const int row = b0 + wr + fq * 4 + j;
                const size_t idx = (size_t)row * 1024 + col;
                const float fg = sigm(acc[0][j] + bof);
                const float ig = sigm(acc[1][j] + boi);
                const float og = sigm(acc[2][j] + boo);
                const float c = fg * cxp[idx] + ig * gupd[idx];
                const float h = og * tanhf(c);
                cxp[idx] = c;
                hxp[idx] = h;
                outs[idx] = h;
                hxbf[idx] = f2bf(h);
            }

            if (TIER == 3 && t + 1 < 256) {  // convert next step's x during S4 phase
                const int idx = bid * 256 + tid;
                f4 v = ((const f4*)xf32)[(size_t)(t + 1) * 65536 + idx];
                us4 o;
                o[0] = f2bf(v[0]); o[1] = f2bf(v[1]); o[2] = f2bf(v[2]); o[3] = f2bf(v[3]);
                ((us4*)xin)[((t + 1) & 1) * 65536 + idx] = o;
            }
        }
        gbar(bar);
    }
}

extern "C" void kernel_launch(void* const* d_in, const int* in_sizes, int n_in,
                              void* d_out, int out_size, void* d_ws, size_t ws_size,
                              hipStream_t stream) {
    const float* inputs = (const float*)d_in[0];
    const float* Wg = (const float*)d_in[1];
    const float* bg = (const float*)d_in[2];
    const float* Wq = (const float*)d_in[3];
    const float* bq = (const float*)d_in[4];
    const float* Wk = (const float*)d_in[5];
    const float* bk = (const float*)d_in[6];
    const float* Wv = (const float*)d_in[7];
    const float* bv = (const float*)d_in[8];
    const float* Wo = (const float*)d_in[9];
    const float* bo = (const float*)d_in[10];
    float* out = (float*)d_out;
    (void)in_sizes; (void)n_in; (void)out_size;

    char* ws = (char*)d_ws;
    size_t off = 0;
    auto alloc = [&](size_t bytes) -> void* {
        void* p = ws + off;
        off += (bytes + 255) & ~(size_t)255;
        return p;
    };
    int*            bar   = (int*)alloc(256);
    unsigned short* wgT   = (unsigned short*)alloc((size_t)4096 * 2048 * 2);
    unsigned short* wqkvT = (unsigned short*)alloc((size_t)3 * 3072 * 1024 * 2);
    unsigned short* woT   = (unsigned short*)alloc((size_t)3 * 1024 * 1024 * 2);
    unsigned short* hxbf  = (unsigned short*)alloc((size_t)256 * 1024 * 2);
    unsigned short* prebf = (unsigned short*)alloc((size_t)3 * 256 * 1024 * 2);
    float*          gupd  = (float*)alloc((size_t)256 * 1024 * 4);
    unsigned short* qkvbf = (unsigned short*)alloc((size_t)3 * 256 * 3072 * 2);
    unsigned short* aobf  = (unsigned short*)alloc((size_t)3 * 256 * 1024 * 2);
    unsigned short* xbfs  = (unsigned short*)alloc((size_t)2 * 256 * 1024 * 2);
    const size_t off_base = off;
    unsigned short* xbf   = (unsigned short*)alloc((size_t)65536 * 1024 * 2);
    const size_t off_t2 = off;
    unsigned short* xpre  = (unsigned short*)alloc((size_t)65536 * 4096 * 2);
    const size_t off_t1 = off;

    const int tier = (ws_size >= off_t1) ? 1 : (ws_size >= off_t2 ? 2 : 3);
    if (ws_size < off_base) return;  // cannot run

    hipMemsetAsync(bar, 0, 256, stream);
    hipMemsetAsync(hxbf, 0, (size_t)256 * 1024 * 2, stream);
    hipMemsetAsync(out + OUT_CX_OFF, 0, (size_t)256 * 1024 * 4, stream);

    // one-time weight convert+transpose
    for (int g = 0; g < 4; ++g)
        k_transpose<<<dim3(32, 64), 256, 0, stream>>>(
            Wg + (size_t)g * 2048 * 1024, wgT + (size_t)g * 1024 * 2048, 2048, 1024);
    const float* wsrc[3] = {Wq, Wk, Wv};
    for (int g = 0; g < 3; ++g)
        for (int wi = 0; wi < 3; ++wi)
            k_transpose<<<dim3(32, 32), 256, 0, stream>>>(
                wsrc[wi] + (size_t)g * 1024 * 1024,
                wqkvT + (size_t)g * 3072 * 1024 + (size_t)wi * 1024 * 1024, 1024, 1024);
    for (int g = 0; g < 3; ++g)
        k_transpose<<<dim3(32, 32), 256, 0, stream>>>(
            Wo + (size_t)g * 1024 * 1024, woT + (size_t)g * 1024 * 1024, 1024, 1024);

    if (tier <= 2) k_x2bf<<<2048, 256, 0, stream>>>(inputs, xbf, 16777216);
    if (tier == 1) k_xpre<<<dim3(32, 512), 256, 0, stream>>>(xbf, wgT, bg, xpre);

    if (tier == 1)
        k_seq<1><<<NBLK, 256, 0, stream>>>(xpre, inputs, wgT, bg, wqkvT, bq, bk, bv,
                                           woT, bo, hxbf, prebf, gupd, qkvbf, aobf, out, bar);
    else if (tier == 2)
        k_seq<2><<<NBLK, 256, 0, stream>>>(xbf, inputs, wgT, bg, wqkvT, bq, bk, bv,
                                           woT, bo, hxbf, prebf, gupd, qkvbf, aobf, out, bar);
    else
        k_seq<3><<<NBLK, 256, 0, stream>>>(xbfs, inputs, wgT, bg, wqkvT, bq, bk, bv,
                                           woT, bo, hxbf, prebf, gupd, qkvbf, aobf, out, bar);
}

// Round 5
// 30547.635 us; speedup vs baseline: 1.7200x; 1.7200x over previous
//
#include <hip/hip_runtime.h>

typedef __attribute__((ext_vector_type(8))) short bf8;
typedef __attribute__((ext_vector_type(8))) unsigned short us8;
typedef __attribute__((ext_vector_type(4))) unsigned short us4;
typedef __attribute__((ext_vector_type(4))) float f4;

#define NB 256
#define NBLK 256
#define OUT_HX_OFF ((size_t)256 * 256 * 1024)
#define OUT_CX_OFF (OUT_HX_OFF + (size_t)256 * 1024)

static __device__ __forceinline__ unsigned short f2bf(float f) {
    unsigned u = __builtin_bit_cast(unsigned, f);
    return (unsigned short)((u + 0x7FFFu + ((u >> 16) & 1u)) >> 16);
}
static __device__ __forceinline__ float bf2f(unsigned short h) {
    return __builtin_bit_cast(float, (unsigned)h << 16);
}
static __device__ __forceinline__ float sigm(float x) {
    return 1.0f / (1.0f + __expf(-x));
}

#define MFMA16(a, b, c) __builtin_amdgcn_mfma_f32_16x16x32_bf16(a, b, c, 0, 0, 0)

#define GLDS16(g, l)                                                        \
    __builtin_amdgcn_global_load_lds(                                       \
        (const __attribute__((address_space(1))) void*)(g),                 \
        (__attribute__((address_space(3))) void*)(l), 16, 0, 0)

#define WAITV(n) asm volatile("s_waitcnt vmcnt(" #n ")" ::: "memory")
#define WAITL0 asm volatile("s_waitcnt lgkmcnt(0)" ::: "memory")
#define BARRIER                                                             \
    do {                                                                    \
        __builtin_amdgcn_s_barrier();                                       \
        __builtin_amdgcn_sched_barrier(0);                                  \
    } while (0)

// Stage R rows x 64 bf16 cols into LDS (linear row-major, 128B rows) via
// global_load_lds.  Source chunk is pre-swizzled (chunk ^= row&7) so the
// read side XORs the same way -> conflict-free-ish ds_read_b128.
template <int R>
static __device__ __forceinline__ void stage64(const unsigned short* g, int gstride,
                                               unsigned short* lds, int wave, int lane) {
#pragma unroll
    for (int j = 0; j < R / 32; ++j) {
        const int seg = wave * (R / 32) + j;
        const int row = seg * 8 + (lane >> 3);
        const int chunk = (lane & 7) ^ (row & 7);
        GLDS16(g + (size_t)row * gstride + chunk * 8, lds + seg * 512);
    }
}

static __device__ __forceinline__ bf8 fragld(const unsigned short* lds, int row, int ck) {
    return *(const bf8*)&lds[row * 64 + (((ck) ^ (row & 7)) << 3)];
}

// Grid barrier, monotonic-counter form.  ALL polls are RELAXED (no buffer_inv
// per poll -- r3's acquire-per-poll was an L2-invalidation storm costing
// ~45us/barrier).  Exactly one release fence (wbl2) before arrival and one
// acquire fence (inv) after exit per block, for cross-XCD data visibility.
// No reset/flip: block waits until counter >= ceil(my_arrival/NBLK)*NBLK.
static __device__ __forceinline__ void gbar(unsigned* bar) {
    __syncthreads();  // all waves' stores retired before tid0 fences
    if (threadIdx.x == 0) {
        __builtin_amdgcn_fence(__ATOMIC_RELEASE, "agent");
        unsigned v = __hip_atomic_fetch_add(bar, 1u, __ATOMIC_RELAXED,
                                            __HIP_MEMORY_SCOPE_AGENT) + 1u;
        const unsigned tgt = ((v + NBLK - 1u) / NBLK) * NBLK;
        while (__hip_atomic_load(bar, __ATOMIC_RELAXED, __HIP_MEMORY_SCOPE_AGENT) < tgt)
            __builtin_amdgcn_s_sleep(8);
        __builtin_amdgcn_fence(__ATOMIC_ACQUIRE, "agent");
    }
    __syncthreads();
}

// ---------------- one-time: f32 -> bf16 convert ----------------
__global__ __launch_bounds__(256) void k_x2bf(const float* __restrict__ src,
                                              unsigned short* __restrict__ dst, int n4) {
    const int stride = gridDim.x * 256;
    for (int i = blockIdx.x * 256 + threadIdx.x; i < n4; i += stride) {
        f4 v = ((const f4*)src)[i];
        us4 o;
        o[0] = f2bf(v[0]); o[1] = f2bf(v[1]); o[2] = f2bf(v[2]); o[3] = f2bf(v[3]);
        ((us4*)dst)[i] = o;
    }
}

// ---------------- one-time: weight transpose f32[K][N] -> bf16[N][K] ----------------
__global__ __launch_bounds__(256) void k_transpose(const float* __restrict__ src,
                                                   unsigned short* __restrict__ dst,
                                                   int K, int N) {
    __shared__ float tile[32][33];
    const int tx = threadIdx.x & 31, ty = threadIdx.x >> 5;
    const int n0 = blockIdx.x * 32, k0 = blockIdx.y * 32;
#pragma unroll
    for (int i = 0; i < 4; ++i) tile[ty + i * 8][tx] = src[(size_t)(k0 + ty + i * 8) * N + n0 + tx];
    __syncthreads();
#pragma unroll
    for (int i = 0; i < 4; ++i)
        dst[(size_t)(n0 + ty + i * 8) * K + k0 + tx] = f2bf(tile[tx][ty + i * 8]);
}

// ---------------- one-time: xpre = X @ Wg_x + bg  (M=65536, N=4096, K=1024) ----------------
__global__ __launch_bounds__(256) void k_xpre(const unsigned short* __restrict__ xbf,
                                              const unsigned short* __restrict__ wgT,
                                              const float* __restrict__ bg,
                                              unsigned short* __restrict__ xpre) {
    __shared__ unsigned short sA[2][128 * 64];
    __shared__ unsigned short sB[2][128 * 64];
    const int tid = threadIdx.x, lane = tid & 63, wave = tid >> 6;
    const int n0 = blockIdx.x * 128;
    const size_t m0 = (size_t)blockIdx.y * 128;
    const int wy = (wave >> 1) * 64, wx = (wave & 1) * 64;
    const int fr = lane & 15, fq = lane >> 4;
    f4 acc[4][4] = {};

    stage64<128>(xbf + m0 * 1024, 1024, sA[0], wave, lane);
    stage64<128>(wgT + (size_t)n0 * 2048, 2048, sB[0], wave, lane);
    WAITV(0); BARRIER;
#pragma unroll
    for (int i = 0; i < 16; ++i) {
        if (i + 1 < 16) {
            stage64<128>(xbf + m0 * 1024 + (i + 1) * 64, 1024, sA[(i + 1) & 1], wave, lane);
            stage64<128>(wgT + (size_t)n0 * 2048 + (i + 1) * 64, 2048, sB[(i + 1) & 1], wave, lane);
        }
        const unsigned short* A = sA[i & 1];
        const unsigned short* Bm = sB[i & 1];
#pragma unroll
        for (int ks = 0; ks < 2; ++ks) {
            bf8 af[4], bfv[4];
#pragma unroll
            for (int mi = 0; mi < 4; ++mi) af[mi] = fragld(A, wy + mi * 16 + fr, ks * 4 + fq);
#pragma unroll
            for (int ni = 0; ni < 4; ++ni) bfv[ni] = fragld(Bm, wx + ni * 16 + fr, ks * 4 + fq);
#pragma unroll
            for (int mi = 0; mi < 4; ++mi)
#pragma unroll
                for (int ni = 0; ni < 4; ++ni)
                    acc[mi][ni] = MFMA16(af[mi], bfv[ni], acc[mi][ni]);
        }
        if (i + 1 < 16) { WAITL0; WAITV(0); BARRIER; }
    }
#pragma unroll
    for (int mi = 0; mi < 4; ++mi)
#pragma unroll
        for (int ni = 0; ni < 4; ++ni) {
            const int col = n0 + wx + ni * 16 + fr;
            const float b = bg[col];
#pragma unroll
            for (int j = 0; j < 4; ++j) {
                const size_t row = m0 + wy + mi * 16 + fq * 4 + j;
                xpre[row * 4096 + col] = f2bf(acc[mi][ni][j] + b);
            }
        }
}

// ---------------- persistent kernel: all 256 timesteps, 4 phases/step ----------------
// TIER 1: xin = xpre [T][256][4096] (bg already folded in).
// TIER 2: xin = xbf  [T][256][1024].
// TIER 3: xin = small double-buffer [2][256][1024]; x(t+1) converted during S4.
template <int TIER>
__global__ __launch_bounds__(256, 1) void k_seq(
    unsigned short* xin, const float* xf32,
    const unsigned short* wgT, const float* bg,
    const unsigned short* wqkvT, const float* bq, const float* bk, const float* bv,
    const unsigned short* woT, const float* bo,
    unsigned short* hxbf, unsigned short* prebf, float* gupd,
    unsigned short* qkvbf, unsigned short* aobf,
    float* out, unsigned* bar) {
    __shared__ unsigned short smem[36864];  // 72 KiB, re-carved per phase
    const int tid = threadIdx.x, lane = tid & 63, wave = tid >> 6;
    const int bid = blockIdx.x;
    const int fr = lane & 15, fq = lane >> 4;

    if (TIER == 3) {  // convert x_0 into buffer 0
        const int idx = bid * 256 + tid;
        f4 v = ((const f4*)xf32)[idx];
        us4 o;
        o[0] = f2bf(v[0]); o[1] = f2bf(v[1]); o[2] = f2bf(v[2]); o[3] = f2bf(v[3]);
        ((us4*)xin)[idx] = o;
        gbar(bar);
    }

    for (int t = 0; t < 256; ++t) {
        // ---------------- S1: pre-gate GEMM ----------------
        {
            const int n0 = (bid & 63) * 64, b0 = (bid >> 6) * 64;
            unsigned short* sA = smem;
            unsigned short* sB = smem + 12288;
            constexpr int NT = (TIER == 1) ? 16 : 32;
            const unsigned short* xt;
            if (TIER == 1) xt = xin + (size_t)t * 256 * 4096;
            else if (TIER == 2) xt = xin + (size_t)t * 256 * 1024;
            else xt = xin + (size_t)(t & 1) * 262144;
            const unsigned short* hb = hxbf + (size_t)b0 * 1024;
            const unsigned short* xb = xt + (TIER == 1 ? 0 : (size_t)b0 * 1024);

            auto asrc = [&](int i) -> const unsigned short* {
                if (TIER == 1) return hb + i * 64;
                return i < 16 ? xb + i * 64 : hb + (i - 16) * 64;
            };
            auto bsrc = [&](int i) -> const unsigned short* {
                return wgT + (size_t)n0 * 2048 + (TIER == 1 ? 1024 : 0) + i * 64;
            };
            const int wr = (wave >> 1) * 32, wc = (wave & 1) * 32;
            f4 acc[2][2] = {};

            stage64<64>(asrc(0), 1024, sA, wave, lane);
            stage64<64>(bsrc(0), 2048, sB, wave, lane);
            stage64<64>(asrc(1), 1024, sA + 4096, wave, lane);
            stage64<64>(bsrc(1), 2048, sB + 4096, wave, lane);
            WAITV(4); BARRIER;
#pragma unroll
            for (int i = 0; i < NT; ++i) {
                if (i + 2 < NT) {
                    stage64<64>(asrc(i + 2), 1024, sA + ((i + 2) % 3) * 4096, wave, lane);
                    stage64<64>(bsrc(i + 2), 2048, sB + ((i + 2) % 3) * 4096, wave, lane);
                }
                const unsigned short* A = sA + (i % 3) * 4096;
                const unsigned short* Bm = sB + (i % 3) * 4096;
#pragma unroll
                for (int ks = 0; ks < 2; ++ks) {
                    bf8 a0 = fragld(A, wr + fr, ks * 4 + fq);
                    bf8 a1 = fragld(A, wr + 16 + fr, ks * 4 + fq);
                    bf8 b0v = fragld(Bm, wc + fr, ks * 4 + fq);
                    bf8 b1v = fragld(Bm, wc + 16 + fr, ks * 4 + fq);
                    acc[0][0] = MFMA16(a0, b0v, acc[0][0]);
                    acc[0][1] = MFMA16(a0, b1v, acc[0][1]);
                    acc[1][0] = MFMA16(a1, b0v, acc[1][0]);
                    acc[1][1] = MFMA16(a1, b1v, acc[1][1]);
                }
                if (i < NT - 1) {
                    WAITL0;
                    if (i + 2 < NT) { WAITV(4); } else { WAITV(0); }
                    BARRIER;
                }
            }
#pragma unroll
            for (int mi = 0; mi < 2; ++mi)
#pragma unroll
                for (int ni = 0; ni < 2; ++ni) {
                    const int col = n0 + wc + ni * 16 + fr;
                    const int gg = col >> 10, d = col & 1023;
#pragma unroll
                    for (int j = 0; j < 4; ++j) {
                        const int row = b0 + wr + mi * 16 + fq * 4 + j;
                        float v = acc[mi][ni][j];
                        if (TIER == 1) v += bf2f(xt[(size_t)row * 4096 + col]);
                        else v += bg[col];
                        if (gg == 2) {
                            gupd[(size_t)row * 1024 + d] = tanhf(v);
                        } else {
                            const int gm = (gg == 3) ? 2 : gg;
                            prebf[((size_t)gm * NB + row) * 1024 + d] = f2bf(v);
                        }
                    }
                }
        }
        gbar(bar);

        // ---------------- S2: QKV GEMMs (288 tiles of 128x64 over 256 blocks) ----------------
        {
            unsigned short* sA = smem;           // 3 x 128*64
            unsigned short* sB = smem + 24576;   // 3 x 64*64
            const int wy = (wave >> 1) * 64, wx = (wave & 1) * 32;
            for (int tl = bid; tl < 288; tl += NBLK) {
                WAITL0;  // drain ds_reads of previous tile before re-staging LDS
                const int g = tl / 96, rem = tl % 96;
                const int b0 = (rem / 48) * 128, n0 = (rem % 48) * 64;
                const unsigned short* Aab = prebf + ((size_t)g * NB + b0) * 1024;
                const unsigned short* Bb = wqkvT + ((size_t)g * 3072 + n0) * 1024;
                f4 acc[4][2] = {};

                stage64<128>(Aab, 1024, sA, wave, lane);
                stage64<64>(Bb, 1024, sB, wave, lane);
                stage64<128>(Aab + 64, 1024, sA + 8192, wave, lane);
                stage64<64>(Bb + 64, 1024, sB + 4096, wave, lane);
                WAITV(6); BARRIER;
#pragma unroll
                for (int i = 0; i < 16; ++i) {
                    if (i + 2 < 16) {
                        stage64<128>(Aab + (i + 2) * 64, 1024, sA + ((i + 2) % 3) * 8192, wave, lane);
                        stage64<64>(Bb + (i + 2) * 64, 1024, sB + ((i + 2) % 3) * 4096, wave, lane);
                    }
                    const unsigned short* A = sA + (i % 3) * 8192;
                    const unsigned short* Bm = sB + (i % 3) * 4096;
#pragma unroll
                    for (int ks = 0; ks < 2; ++ks) {
                        bf8 af[4], bv2[2];
#pragma unroll
                        for (int mi = 0; mi < 4; ++mi)
                            af[mi] = fragld(A, wy + mi * 16 + fr, ks * 4 + fq);
#pragma unroll
                        for (int ni = 0; ni < 2; ++ni)
                            bv2[ni] = fragld(Bm, wx + ni * 16 + fr, ks * 4 + fq);
#pragma unroll
                        for (int mi = 0; mi < 4; ++mi)
#pragma unroll
                            for (int ni = 0; ni < 2; ++ni)
                                acc[mi][ni] = MFMA16(af[mi], bv2[ni], acc[mi][ni]);
                    }
                    if (i < 15) {
                        WAITL0;
                        if (i + 2 < 16) { WAITV(6); } else { WAITV(0); }
                        BARRIER;
                    }
                }
#pragma unroll
                for (int mi = 0; mi < 4; ++mi)
#pragma unroll
                    for (int ni = 0; ni < 2; ++ni) {
                        const int col = n0 + wx + ni * 16 + fr;
                        const int which = col >> 10, d = col & 1023;
                        const float* bp = which == 0 ? bq : (which == 1 ? bk : bv);
                        const float bias = bp[g * 1024 + d];
#pragma unroll
                        for (int j = 0; j < 4; ++j) {
                            const int row = b0 + wy + mi * 16 + fq * 4 + j;
                            qkvbf[((size_t)g * NB + row) * 3072 + col] = f2bf(acc[mi][ni][j] + bias);
                        }
                    }
            }
        }
        gbar(bar);

        // ---------------- S3: cross-head attention (1 batch per block) ----------------
        {
            const int b = bid;
            unsigned short* qs = smem;
            unsigned short* ks2 = smem + 3456;
            unsigned short* vs = smem + 6912;
            float* aw = (float*)(smem + 10368);  // [3][16][17]
#pragma unroll
            for (int j = 0; j < 9; ++j) {
                const int lin = j * 256 + tid;
                const int g = lin / 768, n = (lin % 768) * 4;
                us4 dv = *(const us4*)(qkvbf + ((size_t)g * NB + b) * 3072 + n);
                const int part = n >> 10, h = (n >> 6) & 15, c = n & 63;
                unsigned short* base = part == 0 ? qs : (part == 1 ? ks2 : vs);
                *(us4*)&base[(g * 16 + h) * 72 + c] = dv;
            }
            __syncthreads();
            const int h = tid >> 4, kp = tid & 15;
#pragma unroll
            for (int g = 0; g < 3; ++g) {
                float s = 0.f;
#pragma unroll
                for (int dblk = 0; dblk < 8; ++dblk) {
                    us8 qv = *(const us8*)&qs[(g * 16 + h) * 72 + dblk * 8];
                    us8 kv = *(const us8*)&ks2[(g * 16 + kp) * 72 + dblk * 8];
#pragma unroll
                    for (int e = 0; e < 8; ++e) s += bf2f(qv[e]) * bf2f(kv[e]);
                }
                s *= 0.125f;
                float m = s;
#pragma unroll
                for (int off = 8; off; off >>= 1) m = fmaxf(m, __shfl_xor(m, off, 16));
                const float p = __expf(s - m);
                float sum = p;
#pragma unroll
                for (int off = 8; off; off >>= 1) sum += __shfl_xor(sum, off, 16);
                aw[(g * 16 + h) * 17 + kp] = p / sum;
            }
            __syncthreads();
#pragma unroll
            for (int g = 0; g < 3; ++g) {
                float a0 = 0.f, a1 = 0.f, a2 = 0.f, a3 = 0.f;
#pragma unroll
                for (int kk = 0; kk < 16; ++kk) {
                    const float w = aw[(g * 16 + h) * 17 + kk];
                    us4 vv = *(const us4*)&vs[(g * 16 + kk) * 72 + kp * 4];
                    a0 += w * bf2f(vv[0]); a1 += w * bf2f(vv[1]);
                    a2 += w * bf2f(vv[2]); a3 += w * bf2f(vv[3]);
                }
                us4 ov;
                ov[0] = f2bf(a0); ov[1] = f2bf(a1); ov[2] = f2bf(a2); ov[3] = f2bf(a3);
                *(us4*)(aobf + ((size_t)g * NB + b) * 1024 + h * 64 + kp * 4) = ov;
            }
        }
        gbar(bar);

        // ---------------- S4: output-gate GEMMs + cell update ----------------
        {
            unsigned short* sA = smem;          // 3 x 32*64
            unsigned short* sB = smem + 6144;
            const int d0 = (bid & 31) * 32, b0 = (bid >> 5) * 32;
            const int wr = (wave >> 1) * 16, wc = (wave & 1) * 16;
            f4 acc[3] = {};

            auto asrc = [&](int i) -> const unsigned short* {
                return aobf + ((size_t)(i >> 4) * NB + b0) * 1024 + (i & 15) * 64;
            };
            auto bsrc = [&](int i) -> const unsigned short* {
                return woT + ((size_t)(i >> 4) * 1024 + d0) * 1024 + (i & 15) * 64;
            };
            WAITL0;
            stage64<32>(asrc(0), 1024, sA, wave, lane);
            stage64<32>(bsrc(0), 1024, sB, wave, lane);
            stage64<32>(asrc(1), 1024, sA + 2048, wave, lane);
            stage64<32>(bsrc(1), 1024, sB + 2048, wave, lane);
            WAITV(2); BARRIER;
#pragma unroll
            for (int i = 0; i < 48; ++i) {
                if (i + 2 < 48) {
                    stage64<32>(asrc(i + 2), 1024, sA + ((i + 2) % 3) * 2048, wave, lane);
                    stage64<32>(bsrc(i + 2), 1024, sB + ((i + 2) % 3) * 2048, wave, lane);
                }
                const unsigned short* A = sA + (i % 3) * 2048;
                const unsigned short* Bm = sB + (i % 3) * 2048;
#pragma unroll
                for (int ks = 0; ks < 2; ++ks) {
                    bf8 a0 = fragld(A, wr + fr, ks * 4 + fq);
                    bf8 b0v = fragld(Bm, wc + fr, ks * 4 + fq);
                    acc[i >> 4] = MFMA16(a0, b0v, acc[i >> 4]);
                }
                if (i < 47) {
                    WAITL0;
                    if (i + 2 < 48) { WAITV(2); } else { WAITV(0); }
                    BARRIER;
                }
            }

            const int col = d0 + wc + fr;
            const float bof = bo[col], boi = bo[1024 + col], boo = bo[2048 + col];
            float* cxp = out + OUT_CX_OFF;
            float* hxp = out + OUT_HX_OFF;
            float* outs = out + (size_t)t * NB * 1024;
#pragma unroll
            for (int j = 0; j < 4; ++j) {
                const int row = b0 + wr + fq * 4 + j;
                const size_t idx = (size_t)row * 1024 + col;
                const float fg = sigm(acc[0][j] + bof);
                const float ig = sigm(acc[1][j] + boi);
                const float og = sigm(acc[2][j] + boo);
                const float c = fg * cxp[idx] + ig * gupd[idx];
                const float h = og * tanhf(c);
                cxp[idx] = c;
                hxp[idx] = h;
                outs[idx] = h;
                hxbf[idx] = f2bf(h);
            }

            if (TIER == 3 && t + 1 < 256) {  // convert next step's x during S4 phase
                const int idx = bid * 256 + tid;
                f4 v = ((const f4*)xf32)[(size_t)(t + 1) * 65536 + idx];
                us4 o;
                o[0] = f2bf(v[0]); o[1] = f2bf(v[1]); o[2] = f2bf(v[2]); o[3] = f2bf(v[3]);
                ((us4*)xin)[((t + 1) & 1) * 65536 + idx] = o;
            }
        }
        gbar(bar);
    }
}

extern "C" void kernel_launch(void* const* d_in, const int* in_sizes, int n_in,
                              void* d_out, int out_size, void* d_ws, size_t ws_size,
                              hipStream_t stream) {
    const float* inputs = (const float*)d_in[0];
    const float* Wg = (const float*)d_in[1];
    const float* bg = (const float*)d_in[2];
    const float* Wq = (const float*)d_in[3];
    const float* bq = (const float*)d_in[4];
    const float* Wk = (const float*)d_in[5];
    const float* bk = (const float*)d_in[6];
    const float* Wv = (const float*)d_in[7];
    const float* bv = (const float*)d_in[8];
    const float* Wo = (const float*)d_in[9];
    const float* bo = (const float*)d_in[10];
    float* out = (float*)d_out;
    (void)in_sizes; (void)n_in; (void)out_size;

    char* ws = (char*)d_ws;
    size_t off = 0;
    auto alloc = [&](size_t bytes) -> void* {
        void* p = ws + off;
        off += (bytes + 255) & ~(size_t)255;
        return p;
    };
    unsigned*       bar   = (unsigned*)alloc(256);
    unsigned short* wgT   = (unsigned short*)alloc((size_t)4096 * 2048 * 2);
    unsigned short* wqkvT = (unsigned short*)alloc((size_t)3 * 3072 * 1024 * 2);
    unsigned short* woT   = (unsigned short*)alloc((size_t)3 * 1024 * 1024 * 2);
    unsigned short* hxbf  = (unsigned short*)alloc((size_t)256 * 1024 * 2);
    unsigned short* prebf = (unsigned short*)alloc((size_t)3 * 256 * 1024 * 2);
    float*          gupd  = (float*)alloc((size_t)256 * 1024 * 4);
    unsigned short* qkvbf = (unsigned short*)alloc((size_t)3 * 256 * 3072 * 2);
    unsigned short* aobf  = (unsigned short*)alloc((size_t)3 * 256 * 1024 * 2);
    unsigned short* xbfs  = (unsigned short*)alloc((size_t)2 * 256 * 1024 * 2);
    const size_t off_base = off;
    unsigned short* xbf   = (unsigned short*)alloc((size_t)65536 * 1024 * 2);
    const size_t off_t2 = off;
    unsigned short* xpre  = (unsigned short*)alloc((size_t)65536 * 4096 * 2);
    const size_t off_t1 = off;

    const int tier = (ws_size >= off_t1) ? 1 : (ws_size >= off_t2 ? 2 : 3);
    if (ws_size < off_base) return;  // cannot run

    hipMemsetAsync(bar, 0, 256, stream);
    hipMemsetAsync(hxbf, 0, (size_t)256 * 1024 * 2, stream);
    hipMemsetAsync(out + OUT_CX_OFF, 0, (size_t)256 * 1024 * 4, stream);

    // one-time weight convert+transpose
    for (int g = 0; g < 4; ++g)
        k_transpose<<<dim3(32, 64), 256, 0, stream>>>(
            Wg + (size_t)g * 2048 * 1024, wgT + (size_t)g * 1024 * 2048, 2048, 1024);
    const float* wsrc[3] = {Wq, Wk, Wv};
    for (int g = 0; g < 3; ++g)
        for (int wi = 0; wi < 3; ++wi)
            k_transpose<<<dim3(32, 32), 256, 0, stream>>>(
                wsrc[wi] + (size_t)g * 1024 * 1024,
                wqkvT + (size_t)g * 3072 * 1024 + (size_t)wi * 1024 * 1024, 1024, 1024);
    for (int g = 0; g < 3; ++g)
        k_transpose<<<dim3(32, 32), 256, 0, stream>>>(
            Wo + (size_t)g * 1024 * 1024, woT + (size_t)g * 1024 * 1024, 1024, 1024);

    if (tier <= 2) k_x2bf<<<2048, 256, 0, stream>>>(inputs, xbf, 16777216);
    if (tier == 1) k_xpre<<<dim3(32, 512), 256, 0, stream>>>(xbf, wgT, bg, xpre);

    if (tier == 1)
        k_seq<1><<<NBLK, 256, 0, stream>>>(xpre, inputs, wgT, bg, wqkvT, bq, bk, bv,
                                           woT, bo, hxbf, prebf, gupd, qkvbf, aobf, out, bar);
    else if (tier == 2)
        k_seq<2><<<NBLK, 256, 0, stream>>>(xbf, inputs, wgT, bg, wqkvT, bq, bk, bv,
                                           woT, bo, hxbf, prebf, gupd, qkvbf, aobf, out, bar);
    else
        k_seq<3><<<NBLK, 256, 0, stream>>>(xbfs, inputs, wgT, bg, wqkvT, bq, bk, bv,
                                           woT, bo, hxbf, prebf, gupd, qkvbf, aobf, out, bar);
}